// Round 1
// baseline (350.993 us; speedup 1.0000x reference)
//
#include <hip/hip_runtime.h>
#include <cstdint>

#define HQ 32
#define HKV 8
#define D 128
#define PAGE 16
#define SEQB 2048
#define NB 2
#define NBT (SEQB/PAGE)      // 128 block-table entries per sequence
#define NSLOTS (512*16)      // NUM_BLOCKS*PAGE physical slots

#define BM 32                // q-rows per block (x 4 heads)
#define BN 64                // kv tokens per tile
#define PPAD 72              // P row stride (144B, 16B aligned)

typedef __bf16 bf16;
typedef __bf16 bf16x8 __attribute__((ext_vector_type(8)));
typedef float  f32x4  __attribute__((ext_vector_type(4)));

// ---------------- build inverse slot map: inv[phys_slot] = new-token id or -1 ----------------
__global__ __launch_bounds__(256) void build_inv(const int* __restrict__ slots,
                                                 int* __restrict__ inv) {
    int t = blockIdx.x * 256 + threadIdx.x;
    if (t < NB * SEQB) inv[slots[t]] = t;
}

// ---------------- pack K -> [b][hkv][tok][d] bf16 ; V -> [b][hkv][d][tok] bf16 ----------------
__global__ __launch_bounds__(256) void pack_kv(
    const float* __restrict__ knew, const float* __restrict__ vnew,
    const float* __restrict__ kc,   const float* __restrict__ vc,
    const int* __restrict__ btab,   const int* __restrict__ inv,
    bf16* __restrict__ Kp, bf16* __restrict__ Vp)
{
    int gid = blockIdx.x;
    if (gid < 2048) {
        // ---- K: one bf16x8 of one token row per thread (coalesced) ----
        int i   = gid*256 + threadIdx.x;          // 524288 cells
        int d8  = i & 15;
        int sg  = (i >> 4) & (SEQB - 1);
        int hkv = (i >> 15) & 7;
        int b   = i >> 18;
        int phys = btab[b*NBT + (sg >> 4)] * PAGE + (sg & 15);
        int t    = inv[phys];
        const float* src = (t >= 0 ? knew + (size_t)t * (HKV*D)
                                   : kc   + (size_t)phys * (HKV*D)) + hkv*D + d8*8;
        float4 f0 = *(const float4*)src;
        float4 f1 = *(const float4*)(src + 4);
        bf16x8 o;
        o[0]=(bf16)f0.x; o[1]=(bf16)f0.y; o[2]=(bf16)f0.z; o[3]=(bf16)f0.w;
        o[4]=(bf16)f1.x; o[5]=(bf16)f1.y; o[6]=(bf16)f1.z; o[7]=(bf16)f1.w;
        *(bf16x8*)(Kp + ((size_t)(b*HKV + hkv)*SEQB + sg)*D + d8*8) = o;
    } else {
        // ---- V transposed: consecutive lanes = consecutive d (coalesced reads) ----
        int i   = (gid - 2048)*256 + threadIdx.x; // 524288 cells
        int d   = i & 127;
        int tg  = (i >> 7) & 255;                 // 8-token group
        int hkv = (i >> 15) & 7;
        int b   = i >> 18;
        bf16x8 o;
        #pragma unroll
        for (int u = 0; u < 8; ++u) {
            int sg   = tg*8 + u;
            int phys = btab[b*NBT + (sg >> 4)] * PAGE + (sg & 15);
            int t    = inv[phys];
            float v = (t >= 0) ? vnew[(size_t)t * (HKV*D) + hkv*D + d]
                               : vc  [(size_t)phys * (HKV*D) + hkv*D + d];
            o[u] = (bf16)v;
        }
        *(bf16x8*)(Vp + ((size_t)(b*HKV + hkv)*D + d)*SEQB + tg*8) = o;
    }
}

// ---------------- flash attention: 4 waves x (32 q-rows, 1 head), static-max softmax ----------
// Swapped QK^T: S^T = mfma(K, Q)  (A/B frag layouts are identical, so LDS reads unchanged).
// Each lane then owns P of ONE q-row (c) x 4 toks -> P packed with v_cvt_pk_bf16_f32 and
// stored with 8 ds_write_b64/tile (was 32 ds_write_b16). PV-side reads unchanged.
// LDS layouts (XOR-swizzled 16B chunks, no pads):
//   Kt[tok][slot]: slot = (g&8) | ((g&7)^(tok&7)), g = d-chunk (8 bf16)
//   Vt[d][slot]  : slot = tg ^ (d&7),              tg = tok-group (8 toks)
__global__ __launch_bounds__(256, 3) void attn(
    const float* __restrict__ q,
    const bf16* __restrict__ Kp,
    const bf16* __restrict__ Vp,
    float* __restrict__ out)
{
    __shared__ bf16 Kt[BN * D];          // 16 KB
    __shared__ bf16 Vt[D * BN];          // 16 KB
    __shared__ bf16 Pt[4][BM][PPAD];     // 18 KB, per-wave

    const int qt  = 63 - (blockIdx.x & 63);   // reversed: longest first
    const int hkv = blockIdx.x >> 6;
    const int b   = blockIdx.y;

    const int tid  = threadIdx.x;
    const int w    = tid >> 6;           // wave = head-in-group
    const int lane = tid & 63;
    const int c    = lane & 15;
    const int quad = lane >> 4;
    const int hq   = hkv*4 + w;

    const bf16* Kbase = Kp + (size_t)(b*HKV + hkv) * SEQB * D;
    const bf16* Vbase = Vp + (size_t)(b*HKV + hkv) * (size_t)D * SEQB;

    const float CS = 0.08838834764831845f * 1.4426950408889634f; // 1/sqrt(128)*log2(e)

    // Q B-frags (scale folded in): chunk u covers rows qt*32 + u*16 + c
    bf16x8 qf[2][4];
    #pragma unroll
    for (int u = 0; u < 2; ++u) {
        const float* qrow = q + (size_t)(b*SEQB + qt*BM + u*16 + c) * (HQ*D) + hq*D;
        #pragma unroll
        for (int kk = 0; kk < 4; ++kk) {
            float4 f0 = *(const float4*)(qrow + kk*32 + quad*8);
            float4 f1 = *(const float4*)(qrow + kk*32 + quad*8 + 4);
            bf16x8 a;
            a[0]=(bf16)(f0.x*CS); a[1]=(bf16)(f0.y*CS); a[2]=(bf16)(f0.z*CS); a[3]=(bf16)(f0.w*CS);
            a[4]=(bf16)(f1.x*CS); a[5]=(bf16)(f1.y*CS); a[6]=(bf16)(f1.z*CS); a[7]=(bf16)(f1.w*CS);
            qf[u][kk] = a;
        }
    }

    // staging cell offsets (loop-invariant). cell o handles 16B chunk o of the tile.
    int kgo[4], vgo[4];
    #pragma unroll
    for (int it = 0; it < 4; ++it) {
        int o   = tid + it*256;
        int tok = o >> 4, sl = o & 15;
        int g   = (sl & 8) | ((sl & 7) ^ (tok & 7));
        kgo[it] = tok*D + g*8;
        int d = o >> 3, s2 = o & 7;
        int tg = s2 ^ (d & 7);
        vgo[it] = d*SEQB + tg*8;
    }

    float lrun[2];
    f32x4 accO[2][8];
    lrun[0] = 0.f; lrun[1] = 0.f;
    #pragma unroll
    for (int u = 0; u < 2; ++u)
        #pragma unroll
        for (int dt = 0; dt < 8; ++dt) accO[u][dt] = (f32x4){0.f,0.f,0.f,0.f};

    const int jmax = (qt*BM + BM - 1) >> 6;
    const bf16* kgp = Kbase;
    const bf16* vgp = Vbase;

    // prefetch tile 0 into registers
    bf16x8 kpre[4], vpre[4];
    #pragma unroll
    for (int it = 0; it < 4; ++it) {
        kpre[it] = *(const bf16x8*)(kgp + kgo[it]);
        vpre[it] = *(const bf16x8*)(vgp + vgo[it]);
    }

    const int qrow0 = qt*BM + c;         // global q-row of this lane (u=0 block)

    for (int j = 0; j <= jmax; ++j) {
        __syncthreads();   // all waves done reading previous tile
        #pragma unroll
        for (int it = 0; it < 4; ++it) {
            *(bf16x8*)(Kt + (size_t)(tid + it*256)*8) = kpre[it];
            *(bf16x8*)(Vt + (size_t)(tid + it*256)*8) = vpre[it];
        }
        __syncthreads();   // tile ready

        // prefetch next tile; latency overlaps all compute below
        if (j < jmax) {
            kgp += BN*D; vgp += BN;
            #pragma unroll
            for (int it = 0; it < 4; ++it) kpre[it] = *(const bf16x8*)(kgp + kgo[it]);
            #pragma unroll
            for (int it = 0; it < 4; ++it) vpre[it] = *(const bf16x8*)(vgp + vgo[it]);
        }

        const int kb0  = j * BN;
        const bool diag = (j == jmax);

        // ---- S^T = K Q^T (per 16-tok strip), immediate exp2, packed P to LDS ----
        #pragma unroll
        for (int nt = 0; nt < 4; ++nt) {
            const int tok = nt*16 + c;
            f32x4 s0 = (f32x4){0.f,0.f,0.f,0.f};
            f32x4 s1 = (f32x4){0.f,0.f,0.f,0.f};
            __builtin_amdgcn_s_setprio(1);
            #pragma unroll
            for (int kk = 0; kk < 4; ++kk) {
                int sl = ((kk & 2) << 2) | (((kk & 1) * 4 + quad) ^ (tok & 7));
                bf16x8 kb = *(const bf16x8*)(Kt + tok*D + sl*8);
                s0 = __builtin_amdgcn_mfma_f32_16x16x32_bf16(kb, qf[0][kk], s0, 0, 0, 0);
                s1 = __builtin_amdgcn_mfma_f32_16x16x32_bf16(kb, qf[1][kk], s1, 0, 0, 0);
            }
            __builtin_amdgcn_s_setprio(0);
            const int tokg = kb0 + nt*16 + quad*4;   // global tok of element rr=0
            #pragma unroll
            for (int u = 0; u < 2; ++u) {
                f32x4 sv = u ? s1 : s0;
                float p0 = __builtin_amdgcn_exp2f(sv[0]);
                float p1 = __builtin_amdgcn_exp2f(sv[1]);
                float p2 = __builtin_amdgcn_exp2f(sv[2]);
                float p3 = __builtin_amdgcn_exp2f(sv[3]);
                if (diag) {
                    const int qr = qrow0 + u*16;
                    if (tokg     > qr) p0 = 0.0f;
                    if (tokg + 1 > qr) p1 = 0.0f;
                    if (tokg + 2 > qr) p2 = 0.0f;
                    if (tokg + 3 > qr) p3 = 0.0f;
                }
                lrun[u] += (p0 + p1) + (p2 + p3);
                uint32_t r0, r1;
                asm("v_cvt_pk_bf16_f32 %0, %1, %2" : "=v"(r0) : "v"(p0), "v"(p1));
                asm("v_cvt_pk_bf16_f32 %0, %1, %2" : "=v"(r1) : "v"(p2), "v"(p3));
                uint2 pw; pw.x = r0; pw.y = r1;
                *(uint2*)&Pt[w][u*16 + c][nt*16 + quad*4] = pw;   // ds_write_b64
            }
        }

        // ---- O += P V (each V read feeds both row-chunks) ----
        bf16x8 pa00 = *(const bf16x8*)(&Pt[w][c     ][quad*8]);
        bf16x8 pa01 = *(const bf16x8*)(&Pt[w][c     ][32 + quad*8]);
        bf16x8 pa10 = *(const bf16x8*)(&Pt[w][16 + c][quad*8]);
        bf16x8 pa11 = *(const bf16x8*)(&Pt[w][16 + c][32 + quad*8]);
        const int sl0 = ((quad     ) ^ (c & 7)) * 8;
        const int sl1 = ((quad + 4 ) ^ (c & 7)) * 8;
        __builtin_amdgcn_s_setprio(1);
        #pragma unroll
        for (int dt = 0; dt < 8; ++dt) {
            const bf16* vrow = Vt + (size_t)(dt*16 + c) * BN;
            bf16x8 vb0 = *(const bf16x8*)(vrow + sl0);
            accO[0][dt] = __builtin_amdgcn_mfma_f32_16x16x32_bf16(pa00, vb0, accO[0][dt], 0, 0, 0);
            accO[1][dt] = __builtin_amdgcn_mfma_f32_16x16x32_bf16(pa10, vb0, accO[1][dt], 0, 0, 0);
            bf16x8 vb1 = *(const bf16x8*)(vrow + sl1);
            accO[0][dt] = __builtin_amdgcn_mfma_f32_16x16x32_bf16(pa01, vb1, accO[0][dt], 0, 0, 0);
            accO[1][dt] = __builtin_amdgcn_mfma_f32_16x16x32_bf16(pa11, vb1, accO[1][dt], 0, 0, 0);
        }
        __builtin_amdgcn_s_setprio(0);
    }

    // ---- epilogue: reduce row-sums over quads, fetch per-output-row sum, normalize, store ----
    #pragma unroll
    for (int u = 0; u < 2; ++u) {
        float l = lrun[u];
        l += __shfl_xor(l, 16);
        l += __shfl_xor(l, 32);     // now every lane holds total for q-row (u*16 + c)
        #pragma unroll
        for (int rr = 0; rr < 4; ++rr) {
            float lr = __shfl(l, quad*4 + rr);   // sum for row u*16 + quad*4 + rr
            float inv = 1.0f / lr;
            float* orow = out + (size_t)(b*SEQB + qt*BM + u*16 + quad*4 + rr) * (HQ*D) + hq*D;
            #pragma unroll
            for (int dt = 0; dt < 8; ++dt)
                orow[dt*16 + c] = accO[u][dt][rr] * inv;
        }
    }
}

extern "C" void kernel_launch(void* const* d_in, const int* in_sizes, int n_in,
                              void* d_out, int out_size, void* d_ws, size_t ws_size,
                              hipStream_t stream) {
    const float* q     = (const float*)d_in[0];
    const float* knew  = (const float*)d_in[1];
    const float* vnew  = (const float*)d_in[2];
    const float* kc    = (const float*)d_in[3];
    const float* vc    = (const float*)d_in[4];
    const int*   btab  = (const int*)d_in[5];
    const int*   slots = (const int*)d_in[6];
    float*       out   = (float*)d_out;

    // workspace: inv map | packed K | packed V^T  (~16.1 MB)
    int*  inv = (int*)d_ws;
    bf16* Kp  = (bf16*)((char*)d_ws + 65536);
    bf16* Vp  = Kp + (size_t)NB * HKV * SEQB * D;

    hipMemsetAsync(inv, 0xFF, NSLOTS * sizeof(int), stream);
    build_inv<<<(NB*SEQB + 255)/256, 256, 0, stream>>>(slots, inv);
    pack_kv<<<4096, 256, 0, stream>>>(knew, vnew, kc, vc, btab, inv, Kp, Vp);

    dim3 grid(8 * 64, NB);   // x = hkv*64 | qt(reversed), y = batch
    attn<<<grid, 256, 0, stream>>>(q, Kp, Vp, out);
}

// Round 3
// 257.925 us; speedup vs baseline: 1.3608x; 1.3608x over previous
//
#include <hip/hip_runtime.h>
#include <cstdint>

#define HQ 32
#define HKV 8
#define D 128
#define PAGE 16
#define SEQB 2048
#define NB 2
#define NBT (SEQB/PAGE)      // 128 block-table entries per sequence
#define NSLOTS (512*16)      // NUM_BLOCKS*PAGE physical slots

#define BM 32                // q-rows per block (x 4 heads)
#define BN 64                // kv tokens per tile

typedef __bf16 bf16;
typedef __bf16 bf16x8 __attribute__((ext_vector_type(8)));
typedef float  f32x4  __attribute__((ext_vector_type(4)));

typedef __attribute__((address_space(3))) uint32_t lds_u32_t;
typedef __attribute__((address_space(1))) uint32_t glb_u32_t;

__device__ __forceinline__ void gload16(const bf16* g, bf16* l) {
    __builtin_amdgcn_global_load_lds((const glb_u32_t*)g, (lds_u32_t*)l, 16, 0, 0);
}

// ---------------- build inverse slot map: inv[phys_slot] = new-token id or -1 ----------------
__global__ __launch_bounds__(256) void build_inv(const int* __restrict__ slots,
                                                 int* __restrict__ inv) {
    int t = blockIdx.x * 256 + threadIdx.x;
    if (t < NB * SEQB) inv[slots[t]] = t;
}

// ---------------- pack K -> [b][hkv][tok][d] bf16 ; V -> [b][hkv][d][tok'] bf16 --------------
// V columns are PERMUTED within each 64-token tile: physical pos p = 32h + 8g + j holds
// logical tok t = 32h + 4g + (j&3) + 16*(j>>2).  This makes the PV A-fragment the natural
// register order of the QK^T output (zero-shuffle P).
__global__ __launch_bounds__(256) void pack_kv(
    const float* __restrict__ knew, const float* __restrict__ vnew,
    const float* __restrict__ kc,   const float* __restrict__ vc,
    const int* __restrict__ btab,   const int* __restrict__ inv,
    bf16* __restrict__ Kp, bf16* __restrict__ Vp)
{
    int gid = blockIdx.x;
    if (gid < 2048) {
        // ---- K: one bf16x8 of one token row per thread (coalesced) ----
        int i   = gid*256 + threadIdx.x;          // 524288 cells
        int d8  = i & 15;
        int sg  = (i >> 4) & (SEQB - 1);
        int hkv = (i >> 15) & 7;
        int b   = i >> 18;
        int phys = btab[b*NBT + (sg >> 4)] * PAGE + (sg & 15);
        int t    = inv[phys];
        const float* src = (t >= 0 ? knew + (size_t)t * (HKV*D)
                                   : kc   + (size_t)phys * (HKV*D)) + hkv*D + d8*8;
        float4 f0 = *(const float4*)src;
        float4 f1 = *(const float4*)(src + 4);
        bf16x8 o;
        o[0]=(bf16)f0.x; o[1]=(bf16)f0.y; o[2]=(bf16)f0.z; o[3]=(bf16)f0.w;
        o[4]=(bf16)f1.x; o[5]=(bf16)f1.y; o[6]=(bf16)f1.z; o[7]=(bf16)f1.w;
        *(bf16x8*)(Kp + ((size_t)(b*HKV + hkv)*SEQB + sg)*D + d8*8) = o;
    } else {
        // ---- V transposed + column-permuted (reads stay lane-coalesced over d) ----
        int i   = (gid - 2048)*256 + threadIdx.x; // 524288 cells
        int d   = i & 127;
        int tg  = (i >> 7) & 255;                 // physical 8-token group
        int hkv = (i >> 15) & 7;
        int b   = i >> 18;
        int base = (tg >> 3) * 64 + ((tg >> 2) & 1) * 32 + (tg & 3) * 4;
        bf16x8 o;
        #pragma unroll
        for (int u = 0; u < 8; ++u) {
            int sg   = base + (u & 3) + ((u >> 2) << 4);   // logical source token
            int phys = btab[b*NBT + (sg >> 4)] * PAGE + (sg & 15);
            int t    = inv[phys];
            float v = (t >= 0) ? vnew[(size_t)t * (HKV*D) + hkv*D + d]
                               : vc  [(size_t)phys * (HKV*D) + hkv*D + d];
            o[u] = (bf16)v;
        }
        *(bf16x8*)(Vp + ((size_t)(b*HKV + hkv)*D + d)*SEQB + tg*8) = o;
    }
}

// ---------------- flash attention: paired q-tiles (qt, 63-qt) per block, uniform work --------
// 4 waves x (32 q-rows, 1 head).  Swapped QK^T (S^T = mfma(K,Q)); P stays entirely in
// registers (cvt_pk words ARE the PV A-frag under the permuted V column order).
// Double-buffered LDS K/V tiles staged via global_load_lds (pre-swizzled source, linear dest);
// one __syncthreads per tile; next-tile loads in flight under current-tile compute.
// LDS swizzles: Kt[tok][slot]: slot=(g&8)|((g&7)^(tok&7));  Vt[d][slot]: slot=pg^(d&7).
__global__ __launch_bounds__(256, 2) void attn(
    const float* __restrict__ q,
    const bf16* __restrict__ Kp,
    const bf16* __restrict__ Vp,
    float* __restrict__ out)
{
    __shared__ bf16 KT[2][BN * D];       // 2 x 16 KB
    __shared__ bf16 VT[2][BN * D];       // 2 x 16 KB

    const int hkv = blockIdx.x >> 5;
    const int vq  = blockIdx.x & 31;     // pair id: handles qt = 63-vq then qt = vq
    const int b   = blockIdx.y;

    const int tid  = threadIdx.x;
    const int w    = tid >> 6;           // wave = head-in-group
    const int lane = tid & 63;
    const int c    = lane & 15;
    const int quad = lane >> 4;
    const int hq   = hkv*4 + w;

    const bf16* Kbase = Kp + (size_t)(b*HKV + hkv) * SEQB * D;
    const bf16* Vbase = Vp + (size_t)(b*HKV + hkv) * (size_t)D * SEQB;

    const float CS = 0.08838834764831845f * 1.4426950408889634f; // 1/sqrt(128)*log2(e)

    // staging cell offsets (loop-invariant, swizzle folded into the GLOBAL source offset)
    int kgo[4], vgo[4];
    #pragma unroll
    for (int it = 0; it < 4; ++it) {
        int o   = tid + it*256;
        int tok = o >> 4, sl = o & 15;
        int g   = (sl & 8) | ((sl & 7) ^ (tok & 7));
        kgo[it] = tok*D + g*8;
        int d = o >> 3, s2 = o & 7;
        int tg = s2 ^ (d & 7);
        vgo[it] = d*SEQB + tg*8;
    }

    int cur = 0;
    // prologue: stage tile 0 of pass 0 into buffer 0
    #pragma unroll
    for (int it = 0; it < 4; ++it) gload16(Kbase + kgo[it], &KT[0][(tid + it*256)*8]);
    #pragma unroll
    for (int it = 0; it < 4; ++it) gload16(Vbase + vgo[it], &VT[0][(tid + it*256)*8]);

    #pragma unroll 1
    for (int pass = 0; pass < 2; ++pass) {
        const int qt = pass ? vq : 63 - vq;

        // Q B-frags, scale folded in: chunk u covers row qt*32 + u*16 + c
        bf16x8 qf[2][4];
        #pragma unroll
        for (int u = 0; u < 2; ++u) {
            const float* qrow = q + (size_t)(b*SEQB + qt*BM + u*16 + c) * (HQ*D) + hq*D;
            #pragma unroll
            for (int kk = 0; kk < 4; ++kk) {
                float4 f0 = *(const float4*)(qrow + kk*32 + quad*8);
                float4 f1 = *(const float4*)(qrow + kk*32 + quad*8 + 4);
                bf16x8 a;
                a[0]=(bf16)(f0.x*CS); a[1]=(bf16)(f0.y*CS); a[2]=(bf16)(f0.z*CS); a[3]=(bf16)(f0.w*CS);
                a[4]=(bf16)(f1.x*CS); a[5]=(bf16)(f1.y*CS); a[6]=(bf16)(f1.z*CS); a[7]=(bf16)(f1.w*CS);
                qf[u][kk] = a;
            }
        }

        float lrun[2];
        f32x4 accO[2][8];
        lrun[0] = 0.f; lrun[1] = 0.f;
        #pragma unroll
        for (int u = 0; u < 2; ++u)
            #pragma unroll
            for (int dt = 0; dt < 8; ++dt) accO[u][dt] = (f32x4){0.f,0.f,0.f,0.f};

        const int jmax  = (qt*BM + BM - 1) >> 6;
        const int qrow0 = qt*BM + c;

        for (int j = 0; j <= jmax; ++j) {
            __syncthreads();   // tile j landed (vmcnt drain) + all waves done with buf cur^1

            // issue next-tile loads into the other buffer; in flight under compute below
            if (j < jmax) {
                const bf16* kgp = Kbase + (size_t)(j+1)*BN*D;
                const bf16* vgp = Vbase + (j+1)*BN;
                #pragma unroll
                for (int it = 0; it < 4; ++it) gload16(kgp + kgo[it], &KT[cur^1][(tid + it*256)*8]);
                #pragma unroll
                for (int it = 0; it < 4; ++it) gload16(vgp + vgo[it], &VT[cur^1][(tid + it*256)*8]);
            } else if (pass == 0) {
                // stage tile 0 of the second q-tile pass
                #pragma unroll
                for (int it = 0; it < 4; ++it) gload16(Kbase + kgo[it], &KT[cur^1][(tid + it*256)*8]);
                #pragma unroll
                for (int it = 0; it < 4; ++it) gload16(Vbase + vgo[it], &VT[cur^1][(tid + it*256)*8]);
            }

            const bf16* Kt = KT[cur];
            const bf16* Vt = VT[cur];
            const int kb0  = j * BN;
            const bool diag = (j == jmax);

            // ---- S^T = K Q^T (per 16-tok strip), immediate exp2, P packed in registers ----
            uint32_t pw[2][4][2];   // [u][nt][word]
            #pragma unroll
            for (int nt = 0; nt < 4; ++nt) {
                const int tok = nt*16 + c;
                f32x4 s0 = (f32x4){0.f,0.f,0.f,0.f};
                f32x4 s1 = (f32x4){0.f,0.f,0.f,0.f};
                __builtin_amdgcn_s_setprio(1);
                #pragma unroll
                for (int kk = 0; kk < 4; ++kk) {
                    int sl = ((kk & 2) << 2) | (((kk & 1) * 4 + quad) ^ (tok & 7));
                    bf16x8 kb = *(const bf16x8*)(Kt + tok*D + sl*8);
                    s0 = __builtin_amdgcn_mfma_f32_16x16x32_bf16(kb, qf[0][kk], s0, 0, 0, 0);
                    s1 = __builtin_amdgcn_mfma_f32_16x16x32_bf16(kb, qf[1][kk], s1, 0, 0, 0);
                }
                __builtin_amdgcn_s_setprio(0);
                const int tokg = kb0 + nt*16 + quad*4;   // global tok of element rr=0
                #pragma unroll
                for (int u = 0; u < 2; ++u) {
                    f32x4 sv = u ? s1 : s0;
                    float p0 = __builtin_amdgcn_exp2f(sv[0]);
                    float p1 = __builtin_amdgcn_exp2f(sv[1]);
                    float p2 = __builtin_amdgcn_exp2f(sv[2]);
                    float p3 = __builtin_amdgcn_exp2f(sv[3]);
                    if (diag) {
                        const int qr = qrow0 + u*16;
                        if (tokg     > qr) p0 = 0.0f;
                        if (tokg + 1 > qr) p1 = 0.0f;
                        if (tokg + 2 > qr) p2 = 0.0f;
                        if (tokg + 3 > qr) p3 = 0.0f;
                    }
                    lrun[u] += (p0 + p1) + (p2 + p3);
                    asm("v_cvt_pk_bf16_f32 %0, %1, %2" : "=v"(pw[u][nt][0]) : "v"(p0), "v"(p1));
                    asm("v_cvt_pk_bf16_f32 %0, %1, %2" : "=v"(pw[u][nt][1]) : "v"(p2), "v"(p3));
                }
            }

            // ---- O += P V : A-frags are the packed words directly (permuted k-order) ----
            union PA { uint32_t w[4]; bf16x8 v; };
            PA pa00, pa01, pa10, pa11;
            pa00.w[0]=pw[0][0][0]; pa00.w[1]=pw[0][0][1]; pa00.w[2]=pw[0][1][0]; pa00.w[3]=pw[0][1][1];
            pa01.w[0]=pw[0][2][0]; pa01.w[1]=pw[0][2][1]; pa01.w[2]=pw[0][3][0]; pa01.w[3]=pw[0][3][1];
            pa10.w[0]=pw[1][0][0]; pa10.w[1]=pw[1][0][1]; pa10.w[2]=pw[1][1][0]; pa10.w[3]=pw[1][1][1];
            pa11.w[0]=pw[1][2][0]; pa11.w[1]=pw[1][2][1]; pa11.w[2]=pw[1][3][0]; pa11.w[3]=pw[1][3][1];
            const int sl0 = ((quad    ) ^ (c & 7)) * 8;
            const int sl1 = ((quad + 4) ^ (c & 7)) * 8;
            __builtin_amdgcn_s_setprio(1);
            #pragma unroll
            for (int dt = 0; dt < 8; ++dt) {
                const bf16* vrow = Vt + (size_t)(dt*16 + c) * BN;
                bf16x8 vb0 = *(const bf16x8*)(vrow + sl0);
                accO[0][dt] = __builtin_amdgcn_mfma_f32_16x16x32_bf16(pa00.v, vb0, accO[0][dt], 0, 0, 0);
                accO[1][dt] = __builtin_amdgcn_mfma_f32_16x16x32_bf16(pa10.v, vb0, accO[1][dt], 0, 0, 0);
                bf16x8 vb1 = *(const bf16x8*)(vrow + sl1);
                accO[0][dt] = __builtin_amdgcn_mfma_f32_16x16x32_bf16(pa01.v, vb1, accO[0][dt], 0, 0, 0);
                accO[1][dt] = __builtin_amdgcn_mfma_f32_16x16x32_bf16(pa11.v, vb1, accO[1][dt], 0, 0, 0);
            }
            __builtin_amdgcn_s_setprio(0);

            cur ^= 1;
        }

        // ---- epilogue: reduce row-sums over quads, normalize, store ----
        #pragma unroll
        for (int u = 0; u < 2; ++u) {
            float l = lrun[u];
            l += __shfl_xor(l, 16);
            l += __shfl_xor(l, 32);     // every lane holds total for q-row (u*16 + c)
            #pragma unroll
            for (int rr = 0; rr < 4; ++rr) {
                float lr = __shfl(l, quad*4 + rr);   // sum for row u*16 + quad*4 + rr
                float inv = 1.0f / lr;
                float* orow = out + (size_t)(b*SEQB + qt*BM + u*16 + quad*4 + rr) * (HQ*D) + hq*D;
                #pragma unroll
                for (int dt = 0; dt < 8; ++dt)
                    orow[dt*16 + c] = accO[u][dt][rr] * inv;
            }
        }
    }
}

extern "C" void kernel_launch(void* const* d_in, const int* in_sizes, int n_in,
                              void* d_out, int out_size, void* d_ws, size_t ws_size,
                              hipStream_t stream) {
    const float* q     = (const float*)d_in[0];
    const float* knew  = (const float*)d_in[1];
    const float* vnew  = (const float*)d_in[2];
    const float* kc    = (const float*)d_in[3];
    const float* vc    = (const float*)d_in[4];
    const int*   btab  = (const int*)d_in[5];
    const int*   slots = (const int*)d_in[6];
    float*       out   = (float*)d_out;

    // workspace: inv map | packed K | packed V^T  (~16.1 MB)
    int*  inv = (int*)d_ws;
    bf16* Kp  = (bf16*)((char*)d_ws + 65536);
    bf16* Vp  = Kp + (size_t)NB * HKV * SEQB * D;

    hipMemsetAsync(inv, 0xFF, NSLOTS * sizeof(int), stream);
    build_inv<<<(NB*SEQB + 255)/256, 256, 0, stream>>>(slots, inv);
    pack_kv<<<4096, 256, 0, stream>>>(knew, vnew, kc, vc, btab, inv, Kp, Vp);

    dim3 grid(8 * 32, NB);   // x = hkv*32 | pair id, y = batch ; 512 uniform blocks
    attn<<<grid, 256, 0, stream>>>(q, Kp, Vp, out);
}